// Round 1
// baseline (797.546 us; speedup 1.0000x reference)
//
#include <hip/hip_runtime.h>
#include <hip/hip_bf16.h>

// Problem constants
#define B_   8
#define C_   64
#define H_   256
#define W_   256
#define HW_  65536      // H*W
#define CHW  4194304    // C*H*W (per-batch stride of x / projections)
#define F_   16384      // attention feature dim = CI*W
#define KSPLIT 16
#define KCH  1024       // F_ / KSPLIT

typedef __attribute__((ext_vector_type(8)))  short  short8;   // 8 bf16 = 4 VGPRs
typedef __attribute__((ext_vector_type(4)))  float  floatx4;  // MFMA acc

// float -> bf16 bits, round-to-nearest-even
__device__ __forceinline__ unsigned short f2bf(float v) {
    unsigned int u = __builtin_bit_cast(unsigned int, v);
    unsigned int r = u + 0x7fffu + ((u >> 16) & 1u);
    return (unsigned short)(r >> 16);
}
__device__ __forceinline__ float bf2f(unsigned short h) {
    unsigned int u = ((unsigned int)h) << 16;
    return __builtin_bit_cast(float, u);
}

// ---------------------------------------------------------------------------
// ws layout (floats):
//   theta : [0,          33554432)
//   phi   : [33554432,   67108864)   (AtTh/AtTl ushorts alias here after fmat)
//   g     : [67108864,  100663296)
//   yt    : [0,          33554432)   (reuses theta, dead after fmat)
//   fpart : [100663296, 109051904)   B*KSPLIT*256*256 = 8388608
//   wt4   : [109051904, 109068288)
// ---------------------------------------------------------------------------

// ---- prep: transpose the four 64x64 weight matrices ------------------------
__global__ __launch_bounds__(256) void prep_kernel(
    const float* __restrict__ w_phi, const float* __restrict__ w_g,
    const float* __restrict__ w_theta, const float* __restrict__ w_W,
    float* __restrict__ wt4)
{
    int tid = threadIdx.x;
    const float* src[4] = {w_phi, w_g, w_theta, w_W};
#pragma unroll
    for (int m = 0; m < 4; ++m) {
        float* dst = wt4 + m * 4096;
        const float* s = src[m];
#pragma unroll
        for (int r = 0; r < 16; ++r) {
            int idx = r * 256 + tid;
            int o = idx >> 6, c = idx & 63;
            dst[c * 64 + o] = s[idx];
        }
    }
}

// ---- g64: out[b,o,p0+p] = bias[o] + sum_c wt[c][o]*in[b,c,p0+p] (+resid) ---
template<bool RESID>
__global__ __launch_bounds__(256) void g64_kernel(
    const float* __restrict__ in, const float* __restrict__ wt,
    const float* __restrict__ bias, const float* __restrict__ resid,
    float* __restrict__ outp)
{
    __shared__ float sX[16][260];
    __shared__ float sW[16][68];
    int blk = blockIdx.x;
    int b = blk >> 8;
    int p0 = (blk & 255) << 8;
    size_t base = (size_t)b * CHW + p0;
    int tid = threadIdx.x;
    int tp = tid & 31, to = tid >> 5;
    int srow = tid >> 4;
    int scol = (tid & 15) * 4;

    float acc[8][8];
#pragma unroll
    for (int i = 0; i < 8; ++i)
#pragma unroll
        for (int j = 0; j < 8; ++j) acc[i][j] = 0.f;

    for (int c0 = 0; c0 < 64; c0 += 16) {
        float4 xr[4];
#pragma unroll
        for (int r = 0; r < 4; ++r)
            xr[r] = *(const float4*)&in[base + (size_t)(c0 + srow) * HW_ + scol + r * 64];
        float4 wr = *(const float4*)&wt[(c0 + srow) * 64 + scol];
        __syncthreads();
#pragma unroll
        for (int r = 0; r < 4; ++r)
            *(float4*)&sX[srow][scol + r * 64] = xr[r];
        *(float4*)&sW[srow][scol] = wr;
        __syncthreads();
#pragma unroll
        for (int k = 0; k < 16; ++k) {
            float4 x0 = *(const float4*)&sX[k][tp * 4];
            float4 x1 = *(const float4*)&sX[k][128 + tp * 4];
            float4 w0 = *(const float4*)&sW[k][to * 4];
            float4 w1 = *(const float4*)&sW[k][32 + to * 4];
            float xv[8] = {x0.x, x0.y, x0.z, x0.w, x1.x, x1.y, x1.z, x1.w};
            float wv[8] = {w0.x, w0.y, w0.z, w0.w, w1.x, w1.y, w1.z, w1.w};
#pragma unroll
            for (int oo = 0; oo < 8; ++oo)
#pragma unroll
                for (int pp = 0; pp < 8; ++pp)
                    acc[oo][pp] = fmaf(wv[oo], xv[pp], acc[oo][pp]);
        }
    }
#pragma unroll
    for (int oo = 0; oo < 8; ++oo) {
        int o = (oo < 4) ? (to * 4 + oo) : (32 + to * 4 + (oo - 4));
        float bv = bias[o];
        size_t ob0 = base + (size_t)o * HW_ + tp * 4;
        size_t ob1 = ob0 + 128;
        float4 v0 = {acc[oo][0] + bv, acc[oo][1] + bv, acc[oo][2] + bv, acc[oo][3] + bv};
        float4 v1 = {acc[oo][4] + bv, acc[oo][5] + bv, acc[oo][6] + bv, acc[oo][7] + bv};
        if (RESID) {
            float4 r0 = *(const float4*)&resid[ob0];
            float4 r1 = *(const float4*)&resid[ob1];
            v0.x += r0.x; v0.y += r0.y; v0.z += r0.z; v0.w += r0.w;
            v1.x += r1.x; v1.y += r1.y; v1.z += r1.z; v1.w += r1.w;
        }
        *(float4*)&outp[ob0] = v0;
        *(float4*)&outp[ob1] = v1;
    }
}

// ---- fmat (MFMA split-bf16): fpart[b,ks,j,i] = sum_k phi[j,k]*theta[i,k] ---
// f = phi . theta^T via D = A.B: A[m=j][k] = phi_row, B[k][n=i] = theta_row.
// Split fp32 = hi(bf16) + lo(bf16 residual); 3 MFMA passes share one acc.
// Block: 128(j) x 128(i), K-chunk 1024 (KSPLIT=16). 4 waves, 64x64 each.
__global__ __launch_bounds__(256) void fmat_kernel(
    const float* __restrict__ theta, const float* __restrict__ phi,
    float* __restrict__ fpart)
{
    __shared__ unsigned short sPh[128 * 32];  // [j_local][k32] bf16 hi
    __shared__ unsigned short sPl[128 * 32];
    __shared__ unsigned short sTh[128 * 32];  // [i_local][k32]
    __shared__ unsigned short sTl[128 * 32];

    int blk = blockIdx.x;
    int ks = blk & 15;
    int it = (blk >> 4) & 1;
    int jt = (blk >> 5) & 1;
    int b  = blk >> 6;
    int k0 = ks * KCH;
    int i0 = it * 128, j0 = jt * 128;
    const float* phiB = phi   + (size_t)b * CHW + (size_t)j0 * F_ + k0;
    const float* theB = theta + (size_t)b * CHW + (size_t)i0 * F_ + k0;

    int tid  = threadIdx.x;
    int wave = tid >> 6;
    int lane = tid & 63;
    int wj = wave >> 1, wi = wave & 1;
    int frow = lane & 15;          // fragment row (m or n)
    int fkq  = lane >> 4;          // fragment k-quad (8 bf16 each)

    // staging coords: 64B-contiguous per 4 lanes
    int sr = tid >> 2;             // base row 0..63
    int sk = (tid & 3) * 4;        // base k 0..12

    floatx4 acc[4][4];
#pragma unroll
    for (int a = 0; a < 4; ++a)
#pragma unroll
        for (int q = 0; q < 4; ++q) acc[a][q] = (floatx4){0.f, 0.f, 0.f, 0.f};

    for (int kk = 0; kk < KCH; kk += 32) {
        // ---- stage: fp32 -> (hi,lo) bf16 into LDS -----------------------
        float4 pv[4], tv[4];
#pragma unroll
        for (int q = 0; q < 4; ++q) {
            int row = sr + (q & 1) * 64;
            int ko  = sk + (q >> 1) * 16;
            pv[q] = *(const float4*)&phiB[(size_t)row * F_ + kk + ko];
            tv[q] = *(const float4*)&theB[(size_t)row * F_ + kk + ko];
        }
        __syncthreads();
#pragma unroll
        for (int q = 0; q < 4; ++q) {
            int row = sr + (q & 1) * 64;
            int ko  = sk + (q >> 1) * 16;
            int idx = row * 32 + ko;
            float pf[4] = {pv[q].x, pv[q].y, pv[q].z, pv[q].w};
            float tf[4] = {tv[q].x, tv[q].y, tv[q].z, tv[q].w};
            ushort4 ph, pl, th, tl;
            unsigned short* php = (unsigned short*)&ph;
            unsigned short* plp = (unsigned short*)&pl;
            unsigned short* thp = (unsigned short*)&th;
            unsigned short* tlp = (unsigned short*)&tl;
#pragma unroll
            for (int e = 0; e < 4; ++e) {
                unsigned short h = f2bf(pf[e]);
                php[e] = h;
                plp[e] = f2bf(pf[e] - bf2f(h));
                h = f2bf(tf[e]);
                thp[e] = h;
                tlp[e] = f2bf(tf[e] - bf2f(h));
            }
            *(ushort4*)&sPh[idx] = ph;
            *(ushort4*)&sPl[idx] = pl;
            *(ushort4*)&sTh[idx] = th;
            *(ushort4*)&sTl[idx] = tl;
        }
        __syncthreads();

        // ---- fragments + MFMA ------------------------------------------
        short8 bh[4], bl[4];
#pragma unroll
        for (int ii = 0; ii < 4; ++ii) {
            int ridx = (wi * 64 + ii * 16 + frow) * 32 + fkq * 8;
            bh[ii] = *(const short8*)&sTh[ridx];
            bl[ii] = *(const short8*)&sTl[ridx];
        }
#pragma unroll
        for (int jj = 0; jj < 4; ++jj) {
            int ridx = (wj * 64 + jj * 16 + frow) * 32 + fkq * 8;
            short8 ah = *(const short8*)&sPh[ridx];
            short8 al = *(const short8*)&sPl[ridx];
#pragma unroll
            for (int ii = 0; ii < 4; ++ii) {
                acc[jj][ii] = __builtin_amdgcn_mfma_f32_16x16x32_bf16(ah, bh[ii], acc[jj][ii], 0, 0, 0);
                acc[jj][ii] = __builtin_amdgcn_mfma_f32_16x16x32_bf16(ah, bl[ii], acc[jj][ii], 0, 0, 0);
                acc[jj][ii] = __builtin_amdgcn_mfma_f32_16x16x32_bf16(al, bh[ii], acc[jj][ii], 0, 0, 0);
            }
        }
    }

    // ---- store: D row=j_local, col=i_local; col=lane&15, row=(lane>>4)*4+reg
    size_t obase = (size_t)(b * KSPLIT + ks) * 65536;
#pragma unroll
    for (int jj = 0; jj < 4; ++jj) {
#pragma unroll
        for (int ii = 0; ii < 4; ++ii) {
            int i = i0 + wi * 64 + ii * 16 + frow;
#pragma unroll
            for (int r = 0; r < 4; ++r) {
                int j = j0 + wj * 64 + jj * 16 + fkq * 4 + r;
                fpart[obase + (size_t)j * 256 + i] = acc[jj][ii][r];
            }
        }
    }
}

// ---- softmax over i per (b,j); writes transposed split-bf16 A ---------------
// AtTh/AtTl[b][i][j] = hi/lo bf16 of A[i,j] (softmax over i at fixed j).
// Transposed layout makes j (the ymat contraction index) k-minor so ymat can
// stage it with plain vector copies. 2B scatter stores are absorbed by L2
// (At is 2 MB total).
__global__ __launch_bounds__(256) void softmax_kernel(
    const float* __restrict__ fpart,
    unsigned short* __restrict__ AtTh,
    unsigned short* __restrict__ AtTl)
{
    __shared__ float red[8];
    int blk = blockIdx.x;
    int b = blk >> 8, j = blk & 255;
    int i = threadIdx.x;
    float v = 0.f;
#pragma unroll
    for (int ks = 0; ks < KSPLIT; ++ks)
        v += fpart[(size_t)(b * KSPLIT + ks) * 65536 + (size_t)j * 256 + i];
    float m = v;
#pragma unroll
    for (int off = 32; off >= 1; off >>= 1) m = fmaxf(m, __shfl_xor(m, off, 64));
    if ((i & 63) == 0) red[i >> 6] = m;
    __syncthreads();
    m = fmaxf(fmaxf(red[0], red[1]), fmaxf(red[2], red[3]));
    float e = __expf(v - m);
    float s = e;
#pragma unroll
    for (int off = 32; off >= 1; off >>= 1) s += __shfl_xor(s, off, 64);
    if ((i & 63) == 0) red[4 + (i >> 6)] = s;
    __syncthreads();
    s = red[4] + red[5] + red[6] + red[7];
    float a = e / s;
    unsigned short h = f2bf(a);
    unsigned short l = f2bf(a - bf2f(h));
    size_t o = (size_t)b * 65536 + (size_t)i * 256 + j;
    AtTh[o] = h;
    AtTl[o] = l;
}

// ---- ymat (MFMA split-bf16): yt[b,F,i] = sum_j g[b,j,F] * A[i,j] -----------
// D[m=F][n=i] = sum_k A_op[F][k=j] * B_op[i][k=j].
// A_op = g^T: staged with a per-thread 4x4 register transpose + hi/lo split
//   into XOR-swizzled LDS (stride 40 ushorts; octet block XOR (f>>2)&3 keeps
//   ds_write_b64 at <=4-way bank aliasing and frag ds_read_b128 uniform).
// B_op = AtT: already [i][j] split-bf16 in global; plain short8 copies.
// 3 MFMA passes (hh, hl, lh) share one fp32 acc — same numerics as fmat.
// Block: 128(F) x 128(i), full K=256 in chunks of 32. 4 waves, 64x64 each.
// Grid: 8b * 128Ft * 2it = 2048.
__global__ __launch_bounds__(256) void ymat_kernel(
    const float* __restrict__ g,
    const unsigned short* __restrict__ AtTh,
    const unsigned short* __restrict__ AtTl,
    float* __restrict__ yt)
{
    __shared__ __attribute__((aligned(16))) unsigned short sGh[128 * 40];
    __shared__ __attribute__((aligned(16))) unsigned short sGl[128 * 40];
    __shared__ __attribute__((aligned(16))) unsigned short sAh[128 * 40];
    __shared__ __attribute__((aligned(16))) unsigned short sAl[128 * 40];

    int blk = blockIdx.x;
    int it = blk & 1;
    int Ft = (blk >> 1) & 127;
    int b  = blk >> 8;
    int F0 = Ft * 128;
    int i0 = it * 128;
    const float* gB = g + (size_t)b * CHW + F0;
    const unsigned short* ahB = AtTh + (size_t)b * 65536 + (size_t)i0 * 256;
    const unsigned short* alB = AtTl + (size_t)b * 65536 + (size_t)i0 * 256;

    int tid  = threadIdx.x;
    int wave = tid >> 6;
    int lane = tid & 63;
    int wj = wave >> 1, wi = wave & 1;   // wj: F-quadrant, wi: i-quadrant
    int frow = lane & 15;
    int fkq  = lane >> 4;

    // g staging: thread owns a 4x4 (f x j) tile; fq 0..31, jq 0..7
    int fq = tid & 31;
    int jq = tid >> 5;
    // At staging: thread owns 16 ushorts of one i-row
    int ail = tid >> 1;
    int ahf = (tid & 1) * 16;

    floatx4 acc[4][4];
#pragma unroll
    for (int a = 0; a < 4; ++a)
#pragma unroll
        for (int q = 0; q < 4; ++q) acc[a][q] = (floatx4){0.f, 0.f, 0.f, 0.f};

    for (int kk = 0; kk < 256; kk += 32) {
        // ---- global reads (issued before the sync) ----------------------
        float4 gv[4];
#pragma unroll
        for (int d = 0; d < 4; ++d)
            gv[d] = *(const float4*)&gB[(size_t)(kk + jq * 4 + d) * F_ + fq * 4];
        short8 a0h = *(const short8*)&ahB[(size_t)ail * 256 + kk + ahf];
        short8 a1h = *(const short8*)&ahB[(size_t)ail * 256 + kk + ahf + 8];
        short8 a0l = *(const short8*)&alB[(size_t)ail * 256 + kk + ahf];
        short8 a1l = *(const short8*)&alB[(size_t)ail * 256 + kk + ahf + 8];
        __syncthreads();

        // ---- At: linear vector writes ----------------------------------
        *(short8*)&sAh[ail * 40 + ahf]     = a0h;
        *(short8*)&sAh[ail * 40 + ahf + 8] = a1h;
        *(short8*)&sAl[ail * 40 + ahf]     = a0l;
        *(short8*)&sAl[ail * 40 + ahf + 8] = a1l;

        // ---- g: 4x4 register transpose + split, swizzled b64 writes ----
#pragma unroll
        for (int e = 0; e < 4; ++e) {
            ushort4 hq, lq;
            unsigned short* hp = (unsigned short*)&hq;
            unsigned short* lp = (unsigned short*)&lq;
#pragma unroll
            for (int d = 0; d < 4; ++d) {
                float v = ((const float*)&gv[d])[e];
                unsigned short h = f2bf(v);
                hp[d] = h;
                lp[d] = f2bf(v - bf2f(h));
            }
            int f = fq * 4 + e;
            int off = f * 40 + ((((jq >> 1) ^ (f >> 2)) & 3) << 3) + (jq & 1) * 4;
            *(ushort4*)&sGh[off] = hq;
            *(ushort4*)&sGl[off] = lq;
        }
        __syncthreads();

        // ---- fragments + MFMA ------------------------------------------
        short8 bh[4], bl[4];
#pragma unroll
        for (int ii = 0; ii < 4; ++ii) {
            int ridx = (wi * 64 + ii * 16 + frow) * 40 + fkq * 8;
            bh[ii] = *(const short8*)&sAh[ridx];
            bl[ii] = *(const short8*)&sAl[ridx];
        }
#pragma unroll
        for (int jj = 0; jj < 4; ++jj) {
            int f = wj * 64 + jj * 16 + frow;
            int ridx = f * 40 + (((fkq ^ (f >> 2)) & 3) << 3);
            short8 ah = *(const short8*)&sGh[ridx];
            short8 al = *(const short8*)&sGl[ridx];
#pragma unroll
            for (int ii = 0; ii < 4; ++ii) {
                acc[jj][ii] = __builtin_amdgcn_mfma_f32_16x16x32_bf16(ah, bh[ii], acc[jj][ii], 0, 0, 0);
                acc[jj][ii] = __builtin_amdgcn_mfma_f32_16x16x32_bf16(ah, bl[ii], acc[jj][ii], 0, 0, 0);
                acc[jj][ii] = __builtin_amdgcn_mfma_f32_16x16x32_bf16(al, bh[ii], acc[jj][ii], 0, 0, 0);
            }
        }
    }

    // ---- store: D row = F (A-rows), col = i (B-rows = lane&15) ----------
    size_t ybase = (size_t)b * CHW;
#pragma unroll
    for (int jj = 0; jj < 4; ++jj) {
#pragma unroll
        for (int ii = 0; ii < 4; ++ii) {
            int ig = i0 + wi * 64 + ii * 16 + frow;
#pragma unroll
            for (int r = 0; r < 4; ++r) {
                int Fg = F0 + wj * 64 + jj * 16 + fkq * 4 + r;
                yt[ybase + (size_t)Fg * 256 + ig] = acc[jj][ii][r];
            }
        }
    }
}

extern "C" void kernel_launch(void* const* d_in, const int* in_sizes, int n_in,
                              void* d_out, int out_size, void* d_ws, size_t ws_size,
                              hipStream_t stream) {
    const float* x   = (const float*)d_in[0];
    const float* ref = (const float*)d_in[1];
    const float* w_g = (const float*)d_in[2];
    const float* b_g = (const float*)d_in[3];
    const float* w_t = (const float*)d_in[4];
    const float* b_t = (const float*)d_in[5];
    const float* w_p = (const float*)d_in[6];
    const float* b_p = (const float*)d_in[7];
    const float* w_W = (const float*)d_in[8];
    const float* b_W = (const float*)d_in[9];
    float* out = (float*)d_out;
    float* ws  = (float*)d_ws;

    float* theta = ws;
    float* phi   = ws + 33554432;
    float* g     = ws + 67108864;
    float* yt    = ws;                    // reuse theta (dead after fmat)
    float* fpart = ws + 100663296;
    float* wt4   = ws + 109051904;
    float* wt_p  = wt4;
    float* wt_g  = wt4 + 4096;
    float* wt_t  = wt4 + 8192;
    float* wt_W  = wt4 + 12288;
    // AtT hi/lo ushort arrays alias phi's region (phi dead after fmat)
    unsigned short* AtTh = (unsigned short*)(ws + 33554432);
    unsigned short* AtTl = AtTh + 524288;

    prep_kernel<<<1, 256, 0, stream>>>(w_p, w_g, w_t, w_W, wt4);
    g64_kernel<false><<<2048, 256, 0, stream>>>(x,   wt_p, b_p, nullptr, phi);
    g64_kernel<false><<<2048, 256, 0, stream>>>(x,   wt_g, b_g, nullptr, g);
    g64_kernel<false><<<2048, 256, 0, stream>>>(ref, wt_t, b_t, nullptr, theta);
    fmat_kernel<<<512, 256, 0, stream>>>(theta, phi, fpart);
    softmax_kernel<<<2048, 256, 0, stream>>>(fpart, AtTh, AtTl);
    ymat_kernel<<<2048, 256, 0, stream>>>(g, AtTh, AtTl, yt);
    g64_kernel<true><<<2048, 256, 0, stream>>>(yt, wt_W, b_W, x, out);
}

// Round 8
// 710.298 us; speedup vs baseline: 1.1228x; 1.1228x over previous
//
#include <hip/hip_runtime.h>
#include <hip/hip_bf16.h>

// Problem constants
#define B_   8
#define C_   64
#define H_   256
#define W_   256
#define HW_  65536      // H*W
#define CHW  4194304    // C*H*W (per-batch stride of x / projections)
#define F_   16384      // attention feature dim = CI*W
#define KSPLIT 16
#define KCH  1024       // F_ / KSPLIT

typedef __attribute__((ext_vector_type(8)))  short  short8;   // 8 bf16 = 4 VGPRs
typedef __attribute__((ext_vector_type(4)))  float  floatx4;  // MFMA acc

// float -> bf16 bits, round-to-nearest-even
__device__ __forceinline__ unsigned short f2bf(float v) {
    unsigned int u = __builtin_bit_cast(unsigned int, v);
    unsigned int r = u + 0x7fffu + ((u >> 16) & 1u);
    return (unsigned short)(r >> 16);
}
__device__ __forceinline__ float bf2f(unsigned short h) {
    unsigned int u = ((unsigned int)h) << 16;
    return __builtin_bit_cast(float, u);
}

// ---------------------------------------------------------------------------
// ws layout (floats):
//   theta : [0,          33554432)
//   phi   : [33554432,   67108864)   (AtTh/AtTl ushorts alias here after fmat)
//   g     : [67108864,  100663296)
//   yt    : [0,          33554432)   (reuses theta, dead after fmat)
//   fpart : [100663296, 109051904)   B*KSPLIT*256*256 = 8388608
//   wt4   : [109051904, 109068288)
// ---------------------------------------------------------------------------

// ---- prep: transpose the four 64x64 weight matrices ------------------------
__global__ __launch_bounds__(256) void prep_kernel(
    const float* __restrict__ w_phi, const float* __restrict__ w_g,
    const float* __restrict__ w_theta, const float* __restrict__ w_W,
    float* __restrict__ wt4)
{
    int tid = threadIdx.x;
    const float* src[4] = {w_phi, w_g, w_theta, w_W};
#pragma unroll
    for (int m = 0; m < 4; ++m) {
        float* dst = wt4 + m * 4096;
        const float* s = src[m];
#pragma unroll
        for (int r = 0; r < 16; ++r) {
            int idx = r * 256 + tid;
            int o = idx >> 6, c = idx & 63;
            dst[c * 64 + o] = s[idx];
        }
    }
}

// ---- fused 1x1-conv passes -------------------------------------------------
// Block: 128 px of one batch, all 64 channels staged in LDS once per input.
// Each pass: out[b,o,p] = bias[o] + sum_c wt[c][o]*in[b,c,p] (+resid).
// Thread tile: 8 outputs (to) x 4 px (tp). K=64 loop, no syncs inside.
template<bool HASRES>
__device__ __forceinline__ void g64_pass(
    const float (*sX)[132], const float (*sW)[68],
    int tp, int to, const float* __restrict__ bias,
    const float* __restrict__ resid, float* __restrict__ outp, size_t base)
{
    float4 acc[8];
#pragma unroll
    for (int i = 0; i < 8; ++i) acc[i] = (float4){0.f, 0.f, 0.f, 0.f};
#pragma unroll 8
    for (int k = 0; k < 64; ++k) {
        float4 xv = *(const float4*)&sX[k][tp * 4];
        float4 w0 = *(const float4*)&sW[k][to * 4];
        float4 w1 = *(const float4*)&sW[k][32 + to * 4];
        float wv[8] = {w0.x, w0.y, w0.z, w0.w, w1.x, w1.y, w1.z, w1.w};
#pragma unroll
        for (int oo = 0; oo < 8; ++oo) {
            acc[oo].x = fmaf(wv[oo], xv.x, acc[oo].x);
            acc[oo].y = fmaf(wv[oo], xv.y, acc[oo].y);
            acc[oo].z = fmaf(wv[oo], xv.z, acc[oo].z);
            acc[oo].w = fmaf(wv[oo], xv.w, acc[oo].w);
        }
    }
#pragma unroll
    for (int oo = 0; oo < 8; ++oo) {
        int o = (oo < 4) ? (to * 4 + oo) : (32 + to * 4 + (oo - 4));
        float bv = bias[o];
        size_t ob = base + (size_t)o * HW_ + tp * 4;
        float4 v = {acc[oo].x + bv, acc[oo].y + bv, acc[oo].z + bv, acc[oo].w + bv};
        if (HASRES) {
            float4 r = *(const float4*)&resid[ob];
            v.x += r.x; v.y += r.y; v.z += r.z; v.w += r.w;
        }
        *(float4*)&outp[ob] = v;
    }
}

// g64x3: three projections in one kernel. x staged once (phi+g share it),
// then ref staged for theta. Saves one full HBM read of x + 2 launches.
__global__ __launch_bounds__(256) void g64x3_kernel(
    const float* __restrict__ x, const float* __restrict__ ref,
    const float* __restrict__ wt4,
    const float* __restrict__ b_p, const float* __restrict__ b_g,
    const float* __restrict__ b_t,
    float* __restrict__ phi, float* __restrict__ gout,
    float* __restrict__ theta)
{
    __shared__ float sX[64][132];
    __shared__ float sW[64][68];
    int blk = blockIdx.x;
    int b  = blk >> 9;                 // 512 blocks per batch
    int p0 = (blk & 511) << 7;         // 128 px per block
    size_t base = (size_t)b * CHW + p0;
    int tid  = threadIdx.x;
    int tp   = tid & 31;
    int to   = tid >> 5;
    int srow = tid >> 4;               // 0..15
    int scol = (tid & 15) * 8;         // 0..120
    int wrow = tid >> 2;               // 0..63
    int wcol = (tid & 3) * 16;

    // stage x + w_phi
#pragma unroll
    for (int q = 0; q < 4; ++q) {
        int c = srow + q * 16;
        const float* sp = &x[base + (size_t)c * HW_ + scol];
        *(float4*)&sX[c][scol]     = *(const float4*)sp;
        *(float4*)&sX[c][scol + 4] = *(const float4*)(sp + 4);
    }
#pragma unroll
    for (int q = 0; q < 4; ++q)
        *(float4*)&sW[wrow][wcol + q * 4] = *(const float4*)&wt4[wrow * 64 + wcol + q * 4];
    __syncthreads();
    g64_pass<false>(sX, sW, tp, to, b_p, nullptr, phi, base);
    __syncthreads();
    // swap weights -> w_g (x tile still resident)
#pragma unroll
    for (int q = 0; q < 4; ++q)
        *(float4*)&sW[wrow][wcol + q * 4] = *(const float4*)&wt4[4096 + wrow * 64 + wcol + q * 4];
    __syncthreads();
    g64_pass<false>(sX, sW, tp, to, b_g, nullptr, gout, base);
    __syncthreads();
    // stage ref + w_theta
#pragma unroll
    for (int q = 0; q < 4; ++q) {
        int c = srow + q * 16;
        const float* sp = &ref[base + (size_t)c * HW_ + scol];
        *(float4*)&sX[c][scol]     = *(const float4*)sp;
        *(float4*)&sX[c][scol + 4] = *(const float4*)(sp + 4);
    }
#pragma unroll
    for (int q = 0; q < 4; ++q)
        *(float4*)&sW[wrow][wcol + q * 4] = *(const float4*)&wt4[8192 + wrow * 64 + wcol + q * 4];
    __syncthreads();
    g64_pass<false>(sX, sW, tp, to, b_t, nullptr, theta, base);
}

// g64f: final W-projection + residual, same structure, single pass.
__global__ __launch_bounds__(256) void g64f_kernel(
    const float* __restrict__ yt, const float* __restrict__ wtW,
    const float* __restrict__ bW, const float* __restrict__ resid,
    float* __restrict__ out)
{
    __shared__ float sX[64][132];
    __shared__ float sW[64][68];
    int blk = blockIdx.x;
    int b  = blk >> 9;
    int p0 = (blk & 511) << 7;
    size_t base = (size_t)b * CHW + p0;
    int tid  = threadIdx.x;
    int tp   = tid & 31;
    int to   = tid >> 5;
    int srow = tid >> 4;
    int scol = (tid & 15) * 8;
    int wrow = tid >> 2;
    int wcol = (tid & 3) * 16;

#pragma unroll
    for (int q = 0; q < 4; ++q) {
        int c = srow + q * 16;
        const float* sp = &yt[base + (size_t)c * HW_ + scol];
        *(float4*)&sX[c][scol]     = *(const float4*)sp;
        *(float4*)&sX[c][scol + 4] = *(const float4*)(sp + 4);
    }
#pragma unroll
    for (int q = 0; q < 4; ++q)
        *(float4*)&sW[wrow][wcol + q * 4] = *(const float4*)&wtW[wrow * 64 + wcol + q * 4];
    __syncthreads();
    g64_pass<true>(sX, sW, tp, to, bW, resid, out, base);
}

// ---- fmat (MFMA split-bf16): fpart[b,ks,j,i] = sum_k phi[j,k]*theta[i,k] ---
// f = phi . theta^T via D = A.B: A[m=j][k] = phi_row, B[k][n=i] = theta_row.
// Split fp32 = hi(bf16) + lo(bf16 residual); 3 MFMA passes share one acc.
// Block: 128(j) x 128(i), K-chunk 1024 (KSPLIT=16). 4 waves, 64x64 each.
// LDS row stride 40 ushorts (80 B): frag ds_read_b128 slot = (row*5)%8 ->
// uniform over 8 slots, 2-way = free (was stride 32 = 8-way on banks {0,16}).
#define FST 40
__global__ __launch_bounds__(256) void fmat_kernel(
    const float* __restrict__ theta, const float* __restrict__ phi,
    float* __restrict__ fpart)
{
    __shared__ unsigned short sPh[128 * FST];  // [j_local][k32] bf16 hi
    __shared__ unsigned short sPl[128 * FST];
    __shared__ unsigned short sTh[128 * FST];  // [i_local][k32]
    __shared__ unsigned short sTl[128 * FST];

    int blk = blockIdx.x;
    int ks = blk & 15;
    int it = (blk >> 4) & 1;
    int jt = (blk >> 5) & 1;
    int b  = blk >> 6;
    int k0 = ks * KCH;
    int i0 = it * 128, j0 = jt * 128;
    const float* phiB = phi   + (size_t)b * CHW + (size_t)j0 * F_ + k0;
    const float* theB = theta + (size_t)b * CHW + (size_t)i0 * F_ + k0;

    int tid  = threadIdx.x;
    int wave = tid >> 6;
    int lane = tid & 63;
    int wj = wave >> 1, wi = wave & 1;
    int frow = lane & 15;          // fragment row (m or n)
    int fkq  = lane >> 4;          // fragment k-quad (8 bf16 each)

    // staging coords: 64B-contiguous per 4 lanes
    int sr = tid >> 2;             // base row 0..63
    int sk = (tid & 3) * 4;        // base k 0..12

    floatx4 acc[4][4];
#pragma unroll
    for (int a = 0; a < 4; ++a)
#pragma unroll
        for (int q = 0; q < 4; ++q) acc[a][q] = (floatx4){0.f, 0.f, 0.f, 0.f};

    for (int kk = 0; kk < KCH; kk += 32) {
        // ---- stage: fp32 -> (hi,lo) bf16 into LDS -----------------------
        float4 pv[4], tv[4];
#pragma unroll
        for (int q = 0; q < 4; ++q) {
            int row = sr + (q & 1) * 64;
            int ko  = sk + (q >> 1) * 16;
            pv[q] = *(const float4*)&phiB[(size_t)row * F_ + kk + ko];
            tv[q] = *(const float4*)&theB[(size_t)row * F_ + kk + ko];
        }
        __syncthreads();
#pragma unroll
        for (int q = 0; q < 4; ++q) {
            int row = sr + (q & 1) * 64;
            int ko  = sk + (q >> 1) * 16;
            int idx = row * FST + ko;
            float pf[4] = {pv[q].x, pv[q].y, pv[q].z, pv[q].w};
            float tf[4] = {tv[q].x, tv[q].y, tv[q].z, tv[q].w};
            ushort4 ph, pl, th, tl;
            unsigned short* php = (unsigned short*)&ph;
            unsigned short* plp = (unsigned short*)&pl;
            unsigned short* thp = (unsigned short*)&th;
            unsigned short* tlp = (unsigned short*)&tl;
#pragma unroll
            for (int e = 0; e < 4; ++e) {
                unsigned short h = f2bf(pf[e]);
                php[e] = h;
                plp[e] = f2bf(pf[e] - bf2f(h));
                h = f2bf(tf[e]);
                thp[e] = h;
                tlp[e] = f2bf(tf[e] - bf2f(h));
            }
            *(ushort4*)&sPh[idx] = ph;
            *(ushort4*)&sPl[idx] = pl;
            *(ushort4*)&sTh[idx] = th;
            *(ushort4*)&sTl[idx] = tl;
        }
        __syncthreads();

        // ---- fragments + MFMA ------------------------------------------
        short8 bh[4], bl[4];
#pragma unroll
        for (int ii = 0; ii < 4; ++ii) {
            int ridx = (wi * 64 + ii * 16 + frow) * FST + fkq * 8;
            bh[ii] = *(const short8*)&sTh[ridx];
            bl[ii] = *(const short8*)&sTl[ridx];
        }
#pragma unroll
        for (int jj = 0; jj < 4; ++jj) {
            int ridx = (wj * 64 + jj * 16 + frow) * FST + fkq * 8;
            short8 ah = *(const short8*)&sPh[ridx];
            short8 al = *(const short8*)&sPl[ridx];
#pragma unroll
            for (int ii = 0; ii < 4; ++ii) {
                acc[jj][ii] = __builtin_amdgcn_mfma_f32_16x16x32_bf16(ah, bh[ii], acc[jj][ii], 0, 0, 0);
                acc[jj][ii] = __builtin_amdgcn_mfma_f32_16x16x32_bf16(ah, bl[ii], acc[jj][ii], 0, 0, 0);
                acc[jj][ii] = __builtin_amdgcn_mfma_f32_16x16x32_bf16(al, bh[ii], acc[jj][ii], 0, 0, 0);
            }
        }
    }

    // ---- store: D row=j_local, col=i_local; col=lane&15, row=(lane>>4)*4+reg
    size_t obase = (size_t)(b * KSPLIT + ks) * 65536;
#pragma unroll
    for (int jj = 0; jj < 4; ++jj) {
#pragma unroll
        for (int ii = 0; ii < 4; ++ii) {
            int i = i0 + wi * 64 + ii * 16 + frow;
#pragma unroll
            for (int r = 0; r < 4; ++r) {
                int j = j0 + wj * 64 + jj * 16 + fkq * 4 + r;
                fpart[obase + (size_t)j * 256 + i] = acc[jj][ii][r];
            }
        }
    }
}

// ---- softmax over i per (b,j); writes transposed split-bf16 A ---------------
__global__ __launch_bounds__(256) void softmax_kernel(
    const float* __restrict__ fpart,
    unsigned short* __restrict__ AtTh,
    unsigned short* __restrict__ AtTl)
{
    __shared__ float red[8];
    int blk = blockIdx.x;
    int b = blk >> 8, j = blk & 255;
    int i = threadIdx.x;
    float v = 0.f;
#pragma unroll
    for (int ks = 0; ks < KSPLIT; ++ks)
        v += fpart[(size_t)(b * KSPLIT + ks) * 65536 + (size_t)j * 256 + i];
    float m = v;
#pragma unroll
    for (int off = 32; off >= 1; off >>= 1) m = fmaxf(m, __shfl_xor(m, off, 64));
    if ((i & 63) == 0) red[i >> 6] = m;
    __syncthreads();
    m = fmaxf(fmaxf(red[0], red[1]), fmaxf(red[2], red[3]));
    float e = __expf(v - m);
    float s = e;
#pragma unroll
    for (int off = 32; off >= 1; off >>= 1) s += __shfl_xor(s, off, 64);
    if ((i & 63) == 0) red[4 + (i >> 6)] = s;
    __syncthreads();
    s = red[4] + red[5] + red[6] + red[7];
    float a = e / s;
    unsigned short h = f2bf(a);
    unsigned short l = f2bf(a - bf2f(h));
    size_t o = (size_t)b * 65536 + (size_t)i * 256 + j;
    AtTh[o] = h;
    AtTl[o] = l;
}

// ---- ymat (MFMA split-bf16): yt[b,F,i] = sum_j g[b,j,F] * A[i,j] -----------
__global__ __launch_bounds__(256) void ymat_kernel(
    const float* __restrict__ g,
    const unsigned short* __restrict__ AtTh,
    const unsigned short* __restrict__ AtTl,
    float* __restrict__ yt)
{
    __shared__ __attribute__((aligned(16))) unsigned short sGh[128 * 40];
    __shared__ __attribute__((aligned(16))) unsigned short sGl[128 * 40];
    __shared__ __attribute__((aligned(16))) unsigned short sAh[128 * 40];
    __shared__ __attribute__((aligned(16))) unsigned short sAl[128 * 40];

    int blk = blockIdx.x;
    int it = blk & 1;
    int Ft = (blk >> 1) & 127;
    int b  = blk >> 8;
    int F0 = Ft * 128;
    int i0 = it * 128;
    const float* gB = g + (size_t)b * CHW + F0;
    const unsigned short* ahB = AtTh + (size_t)b * 65536 + (size_t)i0 * 256;
    const unsigned short* alB = AtTl + (size_t)b * 65536 + (size_t)i0 * 256;

    int tid  = threadIdx.x;
    int wave = tid >> 6;
    int lane = tid & 63;
    int wj = wave >> 1, wi = wave & 1;   // wj: F-quadrant, wi: i-quadrant
    int frow = lane & 15;
    int fkq  = lane >> 4;

    int fq = tid & 31;
    int jq = tid >> 5;
    int ail = tid >> 1;
    int ahf = (tid & 1) * 16;

    floatx4 acc[4][4];
#pragma unroll
    for (int a = 0; a < 4; ++a)
#pragma unroll
        for (int q = 0; q < 4; ++q) acc[a][q] = (floatx4){0.f, 0.f, 0.f, 0.f};

    for (int kk = 0; kk < 256; kk += 32) {
        float4 gv[4];
#pragma unroll
        for (int d = 0; d < 4; ++d)
            gv[d] = *(const float4*)&gB[(size_t)(kk + jq * 4 + d) * F_ + fq * 4];
        short8 a0h = *(const short8*)&ahB[(size_t)ail * 256 + kk + ahf];
        short8 a1h = *(const short8*)&ahB[(size_t)ail * 256 + kk + ahf + 8];
        short8 a0l = *(const short8*)&alB[(size_t)ail * 256 + kk + ahf];
        short8 a1l = *(const short8*)&alB[(size_t)ail * 256 + kk + ahf + 8];
        __syncthreads();

        *(short8*)&sAh[ail * 40 + ahf]     = a0h;
        *(short8*)&sAh[ail * 40 + ahf + 8] = a1h;
        *(short8*)&sAl[ail * 40 + ahf]     = a0l;
        *(short8*)&sAl[ail * 40 + ahf + 8] = a1l;

#pragma unroll
        for (int e = 0; e < 4; ++e) {
            ushort4 hq, lq;
            unsigned short* hp = (unsigned short*)&hq;
            unsigned short* lp = (unsigned short*)&lq;
#pragma unroll
            for (int d = 0; d < 4; ++d) {
                float v = ((const float*)&gv[d])[e];
                unsigned short h = f2bf(v);
                hp[d] = h;
                lp[d] = f2bf(v - bf2f(h));
            }
            int f = fq * 4 + e;
            int off = f * 40 + ((((jq >> 1) ^ (f >> 2)) & 3) << 3) + (jq & 1) * 4;
            *(ushort4*)&sGh[off] = hq;
            *(ushort4*)&sGl[off] = lq;
        }
        __syncthreads();

        short8 bh[4], bl[4];
#pragma unroll
        for (int ii = 0; ii < 4; ++ii) {
            int ridx = (wi * 64 + ii * 16 + frow) * 40 + fkq * 8;
            bh[ii] = *(const short8*)&sAh[ridx];
            bl[ii] = *(const short8*)&sAl[ridx];
        }
#pragma unroll
        for (int jj = 0; jj < 4; ++jj) {
            int f = wj * 64 + jj * 16 + frow;
            int ridx = f * 40 + (((fkq ^ (f >> 2)) & 3) << 3);
            short8 ah = *(const short8*)&sGh[ridx];
            short8 al = *(const short8*)&sGl[ridx];
#pragma unroll
            for (int ii = 0; ii < 4; ++ii) {
                acc[jj][ii] = __builtin_amdgcn_mfma_f32_16x16x32_bf16(ah, bh[ii], acc[jj][ii], 0, 0, 0);
                acc[jj][ii] = __builtin_amdgcn_mfma_f32_16x16x32_bf16(ah, bl[ii], acc[jj][ii], 0, 0, 0);
                acc[jj][ii] = __builtin_amdgcn_mfma_f32_16x16x32_bf16(al, bh[ii], acc[jj][ii], 0, 0, 0);
            }
        }
    }

    size_t ybase = (size_t)b * CHW;
#pragma unroll
    for (int jj = 0; jj < 4; ++jj) {
#pragma unroll
        for (int ii = 0; ii < 4; ++ii) {
            int ig = i0 + wi * 64 + ii * 16 + frow;
#pragma unroll
            for (int r = 0; r < 4; ++r) {
                int Fg = F0 + wj * 64 + jj * 16 + fkq * 4 + r;
                yt[ybase + (size_t)Fg * 256 + ig] = acc[jj][ii][r];
            }
        }
    }
}

extern "C" void kernel_launch(void* const* d_in, const int* in_sizes, int n_in,
                              void* d_out, int out_size, void* d_ws, size_t ws_size,
                              hipStream_t stream) {
    const float* x   = (const float*)d_in[0];
    const float* ref = (const float*)d_in[1];
    const float* w_g = (const float*)d_in[2];
    const float* b_g = (const float*)d_in[3];
    const float* w_t = (const float*)d_in[4];
    const float* b_t = (const float*)d_in[5];
    const float* w_p = (const float*)d_in[6];
    const float* b_p = (const float*)d_in[7];
    const float* w_W = (const float*)d_in[8];
    const float* b_W = (const float*)d_in[9];
    float* out = (float*)d_out;
    float* ws  = (float*)d_ws;

    float* theta = ws;
    float* phi   = ws + 33554432;
    float* g     = ws + 67108864;
    float* yt    = ws;                    // reuse theta (dead after fmat)
    float* fpart = ws + 100663296;
    float* wt4   = ws + 109051904;
    // AtT hi/lo ushort arrays alias phi's region (phi dead after fmat)
    unsigned short* AtTh = (unsigned short*)(ws + 33554432);
    unsigned short* AtTl = AtTh + 524288;

    prep_kernel<<<1, 256, 0, stream>>>(w_p, w_g, w_t, w_W, wt4);
    g64x3_kernel<<<4096, 256, 0, stream>>>(x, ref, wt4, b_p, b_g, b_t,
                                           phi, g, theta);
    fmat_kernel<<<512, 256, 0, stream>>>(theta, phi, fpart);
    softmax_kernel<<<2048, 256, 0, stream>>>(fpart, AtTh, AtTl);
    ymat_kernel<<<2048, 256, 0, stream>>>(g, AtTh, AtTl, yt);
    g64f_kernel<<<4096, 256, 0, stream>>>(yt, wt4 + 12288, b_W, x, out);
}

// Round 13
// 677.046 us; speedup vs baseline: 1.1780x; 1.0491x over previous
//
#include <hip/hip_runtime.h>
#include <hip/hip_bf16.h>

// Problem constants
#define B_   8
#define C_   64
#define H_   256
#define W_   256
#define HW_  65536      // H*W
#define CHW  4194304    // C*H*W (per-batch stride of x / projections)
#define F_   16384      // attention feature dim = CI*W
#define KSPLIT 16
#define KCH  1024       // F_ / KSPLIT

typedef __attribute__((ext_vector_type(8)))  short  short8;   // 8 bf16 = 4 VGPRs
typedef __attribute__((ext_vector_type(4)))  float  floatx4;  // MFMA acc

// float -> bf16 bits, round-to-nearest-even
__device__ __forceinline__ unsigned short f2bf(float v) {
    unsigned int u = __builtin_bit_cast(unsigned int, v);
    unsigned int r = u + 0x7fffu + ((u >> 16) & 1u);
    return (unsigned short)(r >> 16);
}
__device__ __forceinline__ float bf2f(unsigned short h) {
    unsigned int u = ((unsigned int)h) << 16;
    return __builtin_bit_cast(float, u);
}

// ---------------------------------------------------------------------------
// ws layout (floats):
//   theta : [0,          33554432)
//   phi   : [33554432,   67108864)   (AtTh/AtTl ushorts alias here after fmat)
//   g     : [67108864,  100663296)
//   yt    : [0,          33554432)   (reuses theta, dead after fmat)
//   fpart : [100663296, 109051904)   B*KSPLIT*256*256 = 8388608
//     wf  : aliases fpart head (W-frags, live only prep->g64x3, 24576 ushorts)
//   wt4   : [109051904, 109068288)   (only +12288 slice = w_W^T used now)
// ---------------------------------------------------------------------------

// ---- prep: w_W transpose (for g64f) + MFMA W-fragments for phi/g/theta -----
// wf layout: per proj p: hi at [p*8192 + s*8 + j], lo at [p*8192 + 4096 + s*8 + j]
// where s = (mi*2+ks)*64 + lane encodes the A-fragment slot:
//   A[m = mi*16 + (lane&15)][k = ks*32 + (lane>>4)*8 + j]
__global__ __launch_bounds__(256) void prep_kernel(
    const float* __restrict__ w_phi, const float* __restrict__ w_g,
    const float* __restrict__ w_theta, const float* __restrict__ w_W,
    float* __restrict__ wt4, unsigned short* __restrict__ wf)
{
    int tid = threadIdx.x;
    // w_W^T for g64f (wtW at wt4+12288)
#pragma unroll
    for (int r = 0; r < 16; ++r) {
        int idx = r * 256 + tid;
        int o = idx >> 6, c = idx & 63;
        wt4[12288 + c * 64 + o] = w_W[idx];
    }
    const float* srcs[3] = {w_phi, w_g, w_theta};
#pragma unroll
    for (int p = 0; p < 3; ++p) {
        const float* w = srcs[p];
#pragma unroll
        for (int t = 0; t < 2; ++t) {
            int s = tid + t * 256;             // 0..511
            int mi = s >> 7;
            int ks = (s >> 6) & 1;
            int lane = s & 63;
            int frow = lane & 15, fkq = lane >> 4;
#pragma unroll
            for (int j = 0; j < 8; ++j) {
                float v = w[(mi * 16 + frow) * 64 + ks * 32 + fkq * 8 + j];
                unsigned short h = f2bf(v);
                wf[p * 8192 + s * 8 + j] = h;
                wf[p * 8192 + 4096 + s * 8 + j] = f2bf(v - bf2f(h));
            }
        }
    }
}

// ---- g64x3 (MFMA split-bf16): three 1x1-conv projections ------------------
// out[o,px] = bias[o] + sum_c W[o,c] * in[c,px]  ->  D = A(W) . B(X^T)
// Block: 256 px x all 64 out-ch, 4 waves (wave w owns px w*64..w*64+63).
// X staged per 32-ch k-step, register-transposed to [px][c] hi/lo bf16 in
// LDS (stride 40 ushorts = fmat's conflict-free geometry). W frags are
// precomputed in global (wf), loaded as coalesced short8 - no LDS.
// 3 MFMA passes (hh,hl,lh) share one fp32 acc (verified recipe from fmat).
__global__ __launch_bounds__(256) void g64x3_kernel(
    const float* __restrict__ x, const float* __restrict__ ref,
    const unsigned short* __restrict__ wf,
    const float* __restrict__ b_p, const float* __restrict__ b_g,
    const float* __restrict__ b_t,
    float* __restrict__ phi, float* __restrict__ gout,
    float* __restrict__ theta)
{
    __shared__ __attribute__((aligned(16))) unsigned short sXh[256 * 40];
    __shared__ __attribute__((aligned(16))) unsigned short sXl[256 * 40];

    int blk = blockIdx.x;
    int b  = blk >> 8;                 // 256 blocks per batch
    int px0 = (blk & 255) << 8;        // 256 px per block
    size_t bbase = (size_t)b * CHW;
    size_t base = bbase + px0;

    int tid  = threadIdx.x;
    int wave = tid >> 6;
    int lane = tid & 63;
    int frow = lane & 15;
    int fkq  = lane >> 4;
    int o8 = tid >> 6;                 // staging: c-octet = wave
    int q  = tid & 63;                 // staging: px-quad = lane

    const float* biases[3] = {b_p, b_g, b_t};
    float* outs[3] = {phi, gout, theta};

#pragma unroll 1
    for (int proj = 0; proj < 3; ++proj) {
        const float* src = (proj == 2) ? ref : x;
        const unsigned short* wtb = wf + proj * 8192;
        const float* bias = biases[proj];
        float* outp = outs[proj];

        floatx4 acc[4][4];
#pragma unroll
        for (int a = 0; a < 4; ++a)
#pragma unroll
            for (int n = 0; n < 4; ++n) acc[a][n] = (floatx4){0.f, 0.f, 0.f, 0.f};

#pragma unroll 1
        for (int ks = 0; ks < 2; ++ks) {
            // ---- global reads: wave o8 reads c-rows [ks*32+o8*8 .. +7] -----
            float4 v[8];
#pragma unroll
            for (int d = 0; d < 8; ++d)
                v[d] = *(const float4*)&src[base + (size_t)(ks * 32 + o8 * 8 + d) * HW_ + q * 4];
            __syncthreads();   // prior frag reads done before overwrite
            // ---- 4x8 register transpose + hi/lo split -> LDS [px][c] ------
#pragma unroll
            for (int e = 0; e < 4; ++e) {
                short8 hv, lv;
                unsigned short* hp = (unsigned short*)&hv;
                unsigned short* lp = (unsigned short*)&lv;
#pragma unroll
                for (int d = 0; d < 8; ++d) {
                    float val = ((const float*)&v[d])[e];
                    unsigned short h = f2bf(val);
                    hp[d] = h;
                    lp[d] = f2bf(val - bf2f(h));
                }
                int off = (q * 4 + e) * 40 + o8 * 8;
                *(short8*)&sXh[off] = hv;
                *(short8*)&sXl[off] = lv;
            }
            __syncthreads();

            // ---- fragments + MFMA -----------------------------------------
            short8 bh[4], bl[4];
#pragma unroll
            for (int ni = 0; ni < 4; ++ni) {
                int ridx = (wave * 64 + ni * 16 + frow) * 40 + fkq * 8;
                bh[ni] = *(const short8*)&sXh[ridx];
                bl[ni] = *(const short8*)&sXl[ridx];
            }
#pragma unroll
            for (int mi = 0; mi < 4; ++mi) {
                int widx = ((mi * 2 + ks) * 64 + lane) * 8;
                short8 ah = *(const short8*)&wtb[widx];
                short8 al = *(const short8*)&wtb[4096 + widx];
#pragma unroll
                for (int ni = 0; ni < 4; ++ni) {
                    acc[mi][ni] = __builtin_amdgcn_mfma_f32_16x16x32_bf16(ah, bh[ni], acc[mi][ni], 0, 0, 0);
                    acc[mi][ni] = __builtin_amdgcn_mfma_f32_16x16x32_bf16(ah, bl[ni], acc[mi][ni], 0, 0, 0);
                    acc[mi][ni] = __builtin_amdgcn_mfma_f32_16x16x32_bf16(al, bh[ni], acc[mi][ni], 0, 0, 0);
                }
            }
        }

        // ---- store: D col(n)=px=frow, row(m)=o=fkq*4+r; + bias -------------
#pragma unroll
        for (int mi = 0; mi < 4; ++mi) {
            float bv[4];
#pragma unroll
            for (int r = 0; r < 4; ++r) bv[r] = bias[mi * 16 + fkq * 4 + r];
#pragma unroll
            for (int ni = 0; ni < 4; ++ni) {
                int px = px0 + wave * 64 + ni * 16 + frow;
#pragma unroll
                for (int r = 0; r < 4; ++r) {
                    int o = mi * 16 + fkq * 4 + r;
                    outp[bbase + (size_t)o * HW_ + px] = acc[mi][ni][r] + bv[r];
                }
            }
        }
        __syncthreads();   // LDS reuse across projections
    }
}

// ---- g64f: final W-projection + residual (fp32 VALU, unchanged) ------------
template<bool HASRES>
__device__ __forceinline__ void g64_pass(
    const float (*sX)[132], const float (*sW)[68],
    int tp, int to, const float* __restrict__ bias,
    const float* __restrict__ resid, float* __restrict__ outp, size_t base)
{
    float4 acc[8];
#pragma unroll
    for (int i = 0; i < 8; ++i) acc[i] = (float4){0.f, 0.f, 0.f, 0.f};
#pragma unroll 8
    for (int k = 0; k < 64; ++k) {
        float4 xv = *(const float4*)&sX[k][tp * 4];
        float4 w0 = *(const float4*)&sW[k][to * 4];
        float4 w1 = *(const float4*)&sW[k][32 + to * 4];
        float wv[8] = {w0.x, w0.y, w0.z, w0.w, w1.x, w1.y, w1.z, w1.w};
#pragma unroll
        for (int oo = 0; oo < 8; ++oo) {
            acc[oo].x = fmaf(wv[oo], xv.x, acc[oo].x);
            acc[oo].y = fmaf(wv[oo], xv.y, acc[oo].y);
            acc[oo].z = fmaf(wv[oo], xv.z, acc[oo].z);
            acc[oo].w = fmaf(wv[oo], xv.w, acc[oo].w);
        }
    }
#pragma unroll
    for (int oo = 0; oo < 8; ++oo) {
        int o = (oo < 4) ? (to * 4 + oo) : (32 + to * 4 + (oo - 4));
        float bv = bias[o];
        size_t ob = base + (size_t)o * HW_ + tp * 4;
        float4 v = {acc[oo].x + bv, acc[oo].y + bv, acc[oo].z + bv, acc[oo].w + bv};
        if (HASRES) {
            float4 r = *(const float4*)&resid[ob];
            v.x += r.x; v.y += r.y; v.z += r.z; v.w += r.w;
        }
        *(float4*)&outp[ob] = v;
    }
}

__global__ __launch_bounds__(256) void g64f_kernel(
    const float* __restrict__ yt, const float* __restrict__ wtW,
    const float* __restrict__ bW, const float* __restrict__ resid,
    float* __restrict__ out)
{
    __shared__ float sX[64][132];
    __shared__ float sW[64][68];
    int blk = blockIdx.x;
    int b  = blk >> 9;
    int p0 = (blk & 511) << 7;
    size_t base = (size_t)b * CHW + p0;
    int tid  = threadIdx.x;
    int tp   = tid & 31;
    int to   = tid >> 5;
    int srow = tid >> 4;
    int scol = (tid & 15) * 8;
    int wrow = tid >> 2;
    int wcol = (tid & 3) * 16;

#pragma unroll
    for (int q = 0; q < 4; ++q) {
        int c = srow + q * 16;
        const float* sp = &yt[base + (size_t)c * HW_ + scol];
        *(float4*)&sX[c][scol]     = *(const float4*)sp;
        *(float4*)&sX[c][scol + 4] = *(const float4*)(sp + 4);
    }
#pragma unroll
    for (int q = 0; q < 4; ++q)
        *(float4*)&sW[wrow][wcol + q * 4] = *(const float4*)&wtW[wrow * 64 + wcol + q * 4];
    __syncthreads();
    g64_pass<true>(sX, sW, tp, to, bW, resid, out, base);
}

// ---- fmat (MFMA split-bf16): fpart[b,ks,j,i] = sum_k phi[j,k]*theta[i,k] ---
#define FST 40
__global__ __launch_bounds__(256) void fmat_kernel(
    const float* __restrict__ theta, const float* __restrict__ phi,
    float* __restrict__ fpart)
{
    __shared__ unsigned short sPh[128 * FST];  // [j_local][k32] bf16 hi
    __shared__ unsigned short sPl[128 * FST];
    __shared__ unsigned short sTh[128 * FST];  // [i_local][k32]
    __shared__ unsigned short sTl[128 * FST];

    int blk = blockIdx.x;
    int ks = blk & 15;
    int it = (blk >> 4) & 1;
    int jt = (blk >> 5) & 1;
    int b  = blk >> 6;
    int k0 = ks * KCH;
    int i0 = it * 128, j0 = jt * 128;
    const float* phiB = phi   + (size_t)b * CHW + (size_t)j0 * F_ + k0;
    const float* theB = theta + (size_t)b * CHW + (size_t)i0 * F_ + k0;

    int tid  = threadIdx.x;
    int wave = tid >> 6;
    int lane = tid & 63;
    int wj = wave >> 1, wi = wave & 1;
    int frow = lane & 15;
    int fkq  = lane >> 4;

    int sr = tid >> 2;
    int sk = (tid & 3) * 4;

    floatx4 acc[4][4];
#pragma unroll
    for (int a = 0; a < 4; ++a)
#pragma unroll
        for (int q = 0; q < 4; ++q) acc[a][q] = (floatx4){0.f, 0.f, 0.f, 0.f};

    for (int kk = 0; kk < KCH; kk += 32) {
        float4 pv[4], tv[4];
#pragma unroll
        for (int q = 0; q < 4; ++q) {
            int row = sr + (q & 1) * 64;
            int ko  = sk + (q >> 1) * 16;
            pv[q] = *(const float4*)&phiB[(size_t)row * F_ + kk + ko];
            tv[q] = *(const float4*)&theB[(size_t)row * F_ + kk + ko];
        }
        __syncthreads();
#pragma unroll
        for (int q = 0; q < 4; ++q) {
            int row = sr + (q & 1) * 64;
            int ko  = sk + (q >> 1) * 16;
            int idx = row * FST + ko;
            float pf[4] = {pv[q].x, pv[q].y, pv[q].z, pv[q].w};
            float tf[4] = {tv[q].x, tv[q].y, tv[q].z, tv[q].w};
            ushort4 ph, pl, th, tl;
            unsigned short* php = (unsigned short*)&ph;
            unsigned short* plp = (unsigned short*)&pl;
            unsigned short* thp = (unsigned short*)&th;
            unsigned short* tlp = (unsigned short*)&tl;
#pragma unroll
            for (int e = 0; e < 4; ++e) {
                unsigned short h = f2bf(pf[e]);
                php[e] = h;
                plp[e] = f2bf(pf[e] - bf2f(h));
                h = f2bf(tf[e]);
                thp[e] = h;
                tlp[e] = f2bf(tf[e] - bf2f(h));
            }
            *(ushort4*)&sPh[idx] = ph;
            *(ushort4*)&sPl[idx] = pl;
            *(ushort4*)&sTh[idx] = th;
            *(ushort4*)&sTl[idx] = tl;
        }
        __syncthreads();

        short8 bh[4], bl[4];
#pragma unroll
        for (int ii = 0; ii < 4; ++ii) {
            int ridx = (wi * 64 + ii * 16 + frow) * FST + fkq * 8;
            bh[ii] = *(const short8*)&sTh[ridx];
            bl[ii] = *(const short8*)&sTl[ridx];
        }
#pragma unroll
        for (int jj = 0; jj < 4; ++jj) {
            int ridx = (wj * 64 + jj * 16 + frow) * FST + fkq * 8;
            short8 ah = *(const short8*)&sPh[ridx];
            short8 al = *(const short8*)&sPl[ridx];
#pragma unroll
            for (int ii = 0; ii < 4; ++ii) {
                acc[jj][ii] = __builtin_amdgcn_mfma_f32_16x16x32_bf16(ah, bh[ii], acc[jj][ii], 0, 0, 0);
                acc[jj][ii] = __builtin_amdgcn_mfma_f32_16x16x32_bf16(ah, bl[ii], acc[jj][ii], 0, 0, 0);
                acc[jj][ii] = __builtin_amdgcn_mfma_f32_16x16x32_bf16(al, bh[ii], acc[jj][ii], 0, 0, 0);
            }
        }
    }

    size_t obase = (size_t)(b * KSPLIT + ks) * 65536;
#pragma unroll
    for (int jj = 0; jj < 4; ++jj) {
#pragma unroll
        for (int ii = 0; ii < 4; ++ii) {
            int i = i0 + wi * 64 + ii * 16 + frow;
#pragma unroll
            for (int r = 0; r < 4; ++r) {
                int j = j0 + wj * 64 + jj * 16 + fkq * 4 + r;
                fpart[obase + (size_t)j * 256 + i] = acc[jj][ii][r];
            }
        }
    }
}

// ---- softmax over i per (b,j); writes transposed split-bf16 A ---------------
__global__ __launch_bounds__(256) void softmax_kernel(
    const float* __restrict__ fpart,
    unsigned short* __restrict__ AtTh,
    unsigned short* __restrict__ AtTl)
{
    __shared__ float red[8];
    int blk = blockIdx.x;
    int b = blk >> 8, j = blk & 255;
    int i = threadIdx.x;
    float v = 0.f;
#pragma unroll
    for (int ks = 0; ks < KSPLIT; ++ks)
        v += fpart[(size_t)(b * KSPLIT + ks) * 65536 + (size_t)j * 256 + i];
    float m = v;
#pragma unroll
    for (int off = 32; off >= 1; off >>= 1) m = fmaxf(m, __shfl_xor(m, off, 64));
    if ((i & 63) == 0) red[i >> 6] = m;
    __syncthreads();
    m = fmaxf(fmaxf(red[0], red[1]), fmaxf(red[2], red[3]));
    float e = __expf(v - m);
    float s = e;
#pragma unroll
    for (int off = 32; off >= 1; off >>= 1) s += __shfl_xor(s, off, 64);
    if ((i & 63) == 0) red[4 + (i >> 6)] = s;
    __syncthreads();
    s = red[4] + red[5] + red[6] + red[7];
    float a = e / s;
    unsigned short h = f2bf(a);
    unsigned short l = f2bf(a - bf2f(h));
    size_t o = (size_t)b * 65536 + (size_t)i * 256 + j;
    AtTh[o] = h;
    AtTl[o] = l;
}

// ---- ymat (MFMA split-bf16): yt[b,F,i] = sum_j g[b,j,F] * A[i,j] -----------
__global__ __launch_bounds__(256) void ymat_kernel(
    const float* __restrict__ g,
    const unsigned short* __restrict__ AtTh,
    const unsigned short* __restrict__ AtTl,
    float* __restrict__ yt)
{
    __shared__ __attribute__((aligned(16))) unsigned short sGh[128 * 40];
    __shared__ __attribute__((aligned(16))) unsigned short sGl[128 * 40];
    __shared__ __attribute__((aligned(16))) unsigned short sAh[128 * 40];
    __shared__ __attribute__((aligned(16))) unsigned short sAl[128 * 40];

    int blk = blockIdx.x;
    int it = blk & 1;
    int Ft = (blk >> 1) & 127;
    int b  = blk >> 8;
    int F0 = Ft * 128;
    int i0 = it * 128;
    const float* gB = g + (size_t)b * CHW + F0;
    const unsigned short* ahB = AtTh + (size_t)b * 65536 + (size_t)i0 * 256;
    const unsigned short* alB = AtTl + (size_t)b * 65536 + (size_t)i0 * 256;

    int tid  = threadIdx.x;
    int wave = tid >> 6;
    int lane = tid & 63;
    int wj = wave >> 1, wi = wave & 1;
    int frow = lane & 15;
    int fkq  = lane >> 4;

    int fq = tid & 31;
    int jq = tid >> 5;
    int ail = tid >> 1;
    int ahf = (tid & 1) * 16;

    floatx4 acc[4][4];
#pragma unroll
    for (int a = 0; a < 4; ++a)
#pragma unroll
        for (int q = 0; q < 4; ++q) acc[a][q] = (floatx4){0.f, 0.f, 0.f, 0.f};

    for (int kk = 0; kk < 256; kk += 32) {
        float4 gv[4];
#pragma unroll
        for (int d = 0; d < 4; ++d)
            gv[d] = *(const float4*)&gB[(size_t)(kk + jq * 4 + d) * F_ + fq * 4];
        short8 a0h = *(const short8*)&ahB[(size_t)ail * 256 + kk + ahf];
        short8 a1h = *(const short8*)&ahB[(size_t)ail * 256 + kk + ahf + 8];
        short8 a0l = *(const short8*)&alB[(size_t)ail * 256 + kk + ahf];
        short8 a1l = *(const short8*)&alB[(size_t)ail * 256 + kk + ahf + 8];
        __syncthreads();

        *(short8*)&sAh[ail * 40 + ahf]     = a0h;
        *(short8*)&sAh[ail * 40 + ahf + 8] = a1h;
        *(short8*)&sAl[ail * 40 + ahf]     = a0l;
        *(short8*)&sAl[ail * 40 + ahf + 8] = a1l;

#pragma unroll
        for (int e = 0; e < 4; ++e) {
            ushort4 hq, lq;
            unsigned short* hp = (unsigned short*)&hq;
            unsigned short* lp = (unsigned short*)&lq;
#pragma unroll
            for (int d = 0; d < 4; ++d) {
                float v = ((const float*)&gv[d])[e];
                unsigned short h = f2bf(v);
                hp[d] = h;
                lp[d] = f2bf(v - bf2f(h));
            }
            int f = fq * 4 + e;
            int off = f * 40 + ((((jq >> 1) ^ (f >> 2)) & 3) << 3) + (jq & 1) * 4;
            *(ushort4*)&sGh[off] = hq;
            *(ushort4*)&sGl[off] = lq;
        }
        __syncthreads();

        short8 bh[4], bl[4];
#pragma unroll
        for (int ii = 0; ii < 4; ++ii) {
            int ridx = (wi * 64 + ii * 16 + frow) * 40 + fkq * 8;
            bh[ii] = *(const short8*)&sAh[ridx];
            bl[ii] = *(const short8*)&sAl[ridx];
        }
#pragma unroll
        for (int jj = 0; jj < 4; ++jj) {
            int f = wj * 64 + jj * 16 + frow;
            int ridx = f * 40 + (((fkq ^ (f >> 2)) & 3) << 3);
            short8 ah = *(const short8*)&sGh[ridx];
            short8 al = *(const short8*)&sGl[ridx];
#pragma unroll
            for (int ii = 0; ii < 4; ++ii) {
                acc[jj][ii] = __builtin_amdgcn_mfma_f32_16x16x32_bf16(ah, bh[ii], acc[jj][ii], 0, 0, 0);
                acc[jj][ii] = __builtin_amdgcn_mfma_f32_16x16x32_bf16(ah, bl[ii], acc[jj][ii], 0, 0, 0);
                acc[jj][ii] = __builtin_amdgcn_mfma_f32_16x16x32_bf16(al, bh[ii], acc[jj][ii], 0, 0, 0);
            }
        }
    }

    size_t ybase = (size_t)b * CHW;
#pragma unroll
    for (int jj = 0; jj < 4; ++jj) {
#pragma unroll
        for (int ii = 0; ii < 4; ++ii) {
            int ig = i0 + wi * 64 + ii * 16 + frow;
#pragma unroll
            for (int r = 0; r < 4; ++r) {
                int Fg = F0 + wj * 64 + jj * 16 + fkq * 4 + r;
                yt[ybase + (size_t)Fg * 256 + ig] = acc[jj][ii][r];
            }
        }
    }
}

extern "C" void kernel_launch(void* const* d_in, const int* in_sizes, int n_in,
                              void* d_out, int out_size, void* d_ws, size_t ws_size,
                              hipStream_t stream) {
    const float* x   = (const float*)d_in[0];
    const float* ref = (const float*)d_in[1];
    const float* w_g = (const float*)d_in[2];
    const float* b_g = (const float*)d_in[3];
    const float* w_t = (const float*)d_in[4];
    const float* b_t = (const float*)d_in[5];
    const float* w_p = (const float*)d_in[6];
    const float* b_p = (const float*)d_in[7];
    const float* w_W = (const float*)d_in[8];
    const float* b_W = (const float*)d_in[9];
    float* out = (float*)d_out;
    float* ws  = (float*)d_ws;

    float* theta = ws;
    float* phi   = ws + 33554432;
    float* g     = ws + 67108864;
    float* yt    = ws;                    // reuse theta (dead after fmat)
    float* fpart = ws + 100663296;
    float* wt4   = ws + 109051904;
    // W-fragments alias fpart head (dead until fmat)
    unsigned short* wf = (unsigned short*)fpart;
    // AtT hi/lo ushort arrays alias phi's region (phi dead after fmat)
    unsigned short* AtTh = (unsigned short*)(ws + 33554432);
    unsigned short* AtTl = AtTh + 524288;

    prep_kernel<<<1, 256, 0, stream>>>(w_p, w_g, w_t, w_W, wt4, wf);
    g64x3_kernel<<<2048, 256, 0, stream>>>(x, ref, wf, b_p, b_g, b_t,
                                           phi, g, theta);
    fmat_kernel<<<512, 256, 0, stream>>>(theta, phi, fpart);
    softmax_kernel<<<2048, 256, 0, stream>>>(fpart, AtTh, AtTl);
    ymat_kernel<<<2048, 256, 0, stream>>>(g, AtTh, AtTl, yt);
    g64f_kernel<<<4096, 256, 0, stream>>>(yt, wt4 + 12288, b_W, x, out);
}